// Round 20
// baseline (54.040 us; speedup 1.0000x reference)
//
#include <hip/hip_runtime.h>

#define NH 8
#define ND 64
#define NM 32
#define NCH 32   // sub-chunk size
#define NC 32    // num sub-chunks

typedef float f32x4 __attribute__((ext_vector_type(4)));

// ---- 64-lane reduce (DPP rows + readlane bcast) ----
__device__ __forceinline__ float wave_sum_bcast(float x) {
    float s = x;
    s += __int_as_float(__builtin_amdgcn_update_dpp(0, __float_as_int(s), 0x111, 0xf, 0xf, false));
    s += __int_as_float(__builtin_amdgcn_update_dpp(0, __float_as_int(s), 0x112, 0xf, 0xf, false));
    s += __int_as_float(__builtin_amdgcn_update_dpp(0, __float_as_int(s), 0x114, 0xf, 0xf, false));
    s += __int_as_float(__builtin_amdgcn_update_dpp(0, __float_as_int(s), 0x118, 0xf, 0xf, false));
    s += __int_as_float(__builtin_amdgcn_update_dpp(0, __float_as_int(s), 0x142, 0xa, 0xf, false));
    s += __int_as_float(__builtin_amdgcn_update_dpp(0, __float_as_int(s), 0x143, 0xc, 0xf, false));
    return __int_as_float(__builtin_amdgcn_readlane(__float_as_int(s), 63));
}

// ---- Slim stage: K full, A/V sliced to the block's 4 m-rows (cols 8*mblk..8*mblk+7) ----
__device__ __forceinline__ void stage_slim(
    const float* __restrict__ A_bar, const float* __restrict__ K,
    const float* __restrict__ V, const float* __restrict__ beta,
    int g, int hh, int mblk,
    float (*K_l)[ND], float (*A_l)[8], float (*V_l)[8], float* b_l)
{
    const int tid = threadIdx.x;                 // 256 threads
    const int f = tid * 8;
    const int t = f >> 6, off = f & 63;
    const int row = ((g * NCH + t) * NH + hh) * 64 + off;
    *(float4*)&K_l[t][off]     = *(const float4*)(K + row);
    *(float4*)&K_l[t][off + 4] = *(const float4*)(K + row + 4);
    const int t2 = tid >> 3, c = tid & 7;
    const int row2 = ((g * NCH + t2) * NH + hh) * 64 + 8 * mblk + c;
    A_l[t2][c] = A_bar[row2];
    V_l[t2][c] = V[row2];
    if (tid < NCH) b_l[tid] = beta[(g * NCH + tid) * NH + hh];
    __syncthreads();
}

// ---------------- Kernel A: intra scan, single-m 64-lane waves, 8 blocks/CU ----------------
// 1984 blocks (g<31 only: chunk 31's summary is never consumed) x 256 threads.
__global__ __launch_bounds__(256) void intra_kernel(
    const float* __restrict__ A_bar, const float* __restrict__ K,
    const float* __restrict__ V, const float* __restrict__ beta,
    float* __restrict__ totalA, float* __restrict__ buf)
{
    __shared__ float K_l[NCH][ND];
    __shared__ float A_l[NCH][8], V_l[NCH][8];
    __shared__ float b_l[NCH];

    const int blk  = blockIdx.x;         // 0..1983
    const int gh   = blk >> 3;           // g*NH + hh
    const int mblk = blk & 7;
    const int hh   = gh & (NH - 1);
    const int g    = gh >> 3;
    const int tid  = threadIdx.x;
    const int wv   = tid >> 6;           // 0..3
    const int lane = tid & 63;
    const int m    = mblk * 4 + wv;      // 0..31

    stage_slim(A_bar, K, V, beta, g, hh, mblk, K_l, A_l, V_l, b_l);

    float hr = 0.f, hi = 0.f;
    float cr = 1.f, ci = 0.f;
    const int c0 = 2 * wv;

#pragma unroll 4
    for (int t = 0; t < NCH; ++t) {
        const float kd = K_l[t][lane];
        const float b  = b_l[t];
        const float ar = A_l[t][c0], ai = A_l[t][c0 + 1];
        const float vr = V_l[t][c0], vi = V_l[t][c0 + 1];
        const float bk = b * kd;

        const float hkr = wave_sum_bcast(hr * kd);
        const float hki = wave_sum_bcast(hi * kd);

        const float tr = hr - bk * hkr, ti = hi - bk * hki;
        hr = ar * tr - ai * ti + bk * vr;
        hi = ar * ti + ai * tr + bk * vi;

        const float n = cr * ar - ci * ai;
        ci = cr * ai + ci * ar;
        cr = n;
    }

    // buf planar: entry e = gh*NM + m; re at [e*128 + d], im at [e*128 + 64 + d]
    const int e = gh * NM + m;
    buf[e * 128 + lane]      = hr;
    buf[e * 128 + 64 + lane] = hi;
    if (lane == 0) {
        totalA[2 * e]     = cr;
        totalA[2 * e + 1] = ci;
    }
}

// ---------------- Kernel B: single-m 64-lane waves, prefix + final scan (unchanged R19) ----------------
__global__ __launch_bounds__(256) void final_kernel(
    const float* __restrict__ A_bar, const float* __restrict__ K,
    const float* __restrict__ V, const float* __restrict__ beta,
    const float* __restrict__ totalA, const float* __restrict__ buf,
    float* __restrict__ Y)
{
    __shared__ float K_l[NCH][ND];
    __shared__ float A_l[NCH][8], V_l[NCH][8];
    __shared__ float b_l[NCH];

    const int blk  = blockIdx.x;         // 0..2047
    const int gh   = blk >> 3;           // g*NH + hh
    const int mblk = blk & 7;
    const int hh   = gh & (NH - 1);
    const int g    = gh >> 3;
    const int tid  = threadIdx.x;
    const int wv   = tid >> 6;
    const int lane = tid & 63;
    const int m    = mblk * 4 + wv;

    stage_slim(A_bar, K, V, beta, g, hh, mblk, K_l, A_l, V_l, b_l);

    // ---- prefix for this m: fold s = A_gg * s + H_gg over gg < g ----
    float hr = 0.f, hi = 0.f;
    for (int gg = 0; gg < g; ++gg) {
        const int e = (gg * NH + hh) * NM + m;
        const float ar = totalA[2 * e], ai = totalA[2 * e + 1];
        const float fr = buf[e * 128 + lane];
        const float fi = buf[e * 128 + 64 + lane];
        const float n = ar * hr - ai * hi + fr;
        hi = ar * hi + ai * hr + fi;
        hr = n;
    }

    // ---- final scan with init = s_in; state IS the output ----
    const int base_l = g * NCH;
    const int c0 = 2 * wv;
#pragma unroll 4
    for (int t = 0; t < NCH; ++t) {
        const float kd = K_l[t][lane];
        const float b  = b_l[t];
        const float ar = A_l[t][c0], ai = A_l[t][c0 + 1];
        const float vr = V_l[t][c0], vi = V_l[t][c0 + 1];
        const float bk = b * kd;

        const float hkr = wave_sum_bcast(hr * kd);
        const float hki = wave_sum_bcast(hi * kd);

        const float tr = hr - bk * hkr, ti = hi - bk * hki;
        hr = ar * tr - ai * ti + bk * vr;
        hi = ar * ti + ai * tr + bk * vi;

        // Y[b,l,h,2m,d]=Re, Y[b,l,h,2m+1,d]=Im — 256 B/wave contiguous stores
        const int ybase = ((base_l + t) * NH + hh) * (2 * NM) * ND + lane;
        __builtin_nontemporal_store(hr, &Y[ybase + (2 * m) * ND]);
        __builtin_nontemporal_store(hi, &Y[ybase + (2 * m + 1) * ND]);
    }
}

extern "C" void kernel_launch(void* const* d_in, const int* in_sizes, int n_in,
                              void* d_out, int out_size, void* d_ws, size_t ws_size,
                              hipStream_t stream) {
    const float* A_bar = (const float*)d_in[0];
    const float* K     = (const float*)d_in[1];
    const float* V     = (const float*)d_in[2];
    const float* beta  = (const float*)d_in[3];
    float* Y = (float*)d_out;

    float* ws = (float*)d_ws;
    float* totalA = ws;                 // NC*NH*NM*2 = 16384 floats
    float* buf    = ws + 16384;         // finalH planar: 1,048,576 floats (4 MB)

    intra_kernel<<<(NC - 1) * NH * 8, 256, 0, stream>>>(A_bar, K, V, beta, totalA, buf);
    final_kernel<<<NC * NH * 8, 256, 0, stream>>>(A_bar, K, V, beta, totalA, buf, Y);
}

// Round 21
// 53.859 us; speedup vs baseline: 1.0034x; 1.0034x over previous
//
#include <hip/hip_runtime.h>

#define NH 8
#define ND 64
#define NM 32
#define NCH 32   // sub-chunk size
#define NC 32    // num sub-chunks

typedef float f32x4 __attribute__((ext_vector_type(4)));

// ---- 64-lane reduce (DPP rows + readlane bcast) ----
__device__ __forceinline__ float wave_sum_bcast(float x) {
    float s = x;
    s += __int_as_float(__builtin_amdgcn_update_dpp(0, __float_as_int(s), 0x111, 0xf, 0xf, false));
    s += __int_as_float(__builtin_amdgcn_update_dpp(0, __float_as_int(s), 0x112, 0xf, 0xf, false));
    s += __int_as_float(__builtin_amdgcn_update_dpp(0, __float_as_int(s), 0x114, 0xf, 0xf, false));
    s += __int_as_float(__builtin_amdgcn_update_dpp(0, __float_as_int(s), 0x118, 0xf, 0xf, false));
    s += __int_as_float(__builtin_amdgcn_update_dpp(0, __float_as_int(s), 0x142, 0xa, 0xf, false));
    s += __int_as_float(__builtin_amdgcn_update_dpp(0, __float_as_int(s), 0x143, 0xc, 0xf, false));
    return __int_as_float(__builtin_amdgcn_readlane(__float_as_int(s), 63));
}

// ---- Slim stage: K full, A/V sliced to the block's 4 m-rows (cols 8*mblk..8*mblk+7) ----
__device__ __forceinline__ void stage_slim(
    const float* __restrict__ A_bar, const float* __restrict__ K,
    const float* __restrict__ V, const float* __restrict__ beta,
    int g, int hh, int mblk,
    float (*K_l)[ND], float (*A_l)[8], float (*V_l)[8], float* b_l)
{
    const int tid = threadIdx.x;                 // 256 threads
    const int f = tid * 8;
    const int t = f >> 6, off = f & 63;
    const int row = ((g * NCH + t) * NH + hh) * 64 + off;
    *(float4*)&K_l[t][off]     = *(const float4*)(K + row);
    *(float4*)&K_l[t][off + 4] = *(const float4*)(K + row + 4);
    const int t2 = tid >> 3, c = tid & 7;
    const int row2 = ((g * NCH + t2) * NH + hh) * 64 + 8 * mblk + c;
    A_l[t2][c] = A_bar[row2];
    V_l[t2][c] = V[row2];
    if (tid < NCH) b_l[tid] = beta[(g * NCH + tid) * NH + hh];
    __syncthreads();
}

// ---------------- Kernel A: intra scan, single-m 64-lane waves, 8 blocks/CU ----------------
// 1984 blocks (g<31 only: chunk 31's summary is never consumed) x 256 threads.
__global__ __launch_bounds__(256) void intra_kernel(
    const float* __restrict__ A_bar, const float* __restrict__ K,
    const float* __restrict__ V, const float* __restrict__ beta,
    float* __restrict__ totalA, float* __restrict__ buf)
{
    __shared__ float K_l[NCH][ND];
    __shared__ float A_l[NCH][8], V_l[NCH][8];
    __shared__ float b_l[NCH];

    const int blk  = blockIdx.x;         // 0..1983
    const int gh   = blk >> 3;           // g*NH + hh
    const int mblk = blk & 7;
    const int hh   = gh & (NH - 1);
    const int g    = gh >> 3;
    const int tid  = threadIdx.x;
    const int wv   = tid >> 6;           // 0..3
    const int lane = tid & 63;
    const int m    = mblk * 4 + wv;      // 0..31

    stage_slim(A_bar, K, V, beta, g, hh, mblk, K_l, A_l, V_l, b_l);

    float hr = 0.f, hi = 0.f;
    float cr = 1.f, ci = 0.f;
    const int c0 = 2 * wv;

#pragma unroll 4
    for (int t = 0; t < NCH; ++t) {
        const float kd = K_l[t][lane];
        const float b  = b_l[t];
        const float ar = A_l[t][c0], ai = A_l[t][c0 + 1];
        const float vr = V_l[t][c0], vi = V_l[t][c0 + 1];
        const float bk = b * kd;

        const float hkr = wave_sum_bcast(hr * kd);
        const float hki = wave_sum_bcast(hi * kd);

        const float tr = hr - bk * hkr, ti = hi - bk * hki;
        hr = ar * tr - ai * ti + bk * vr;
        hi = ar * ti + ai * tr + bk * vi;

        const float n = cr * ar - ci * ai;
        ci = cr * ai + ci * ar;
        cr = n;
    }

    // buf planar: entry e = gh*NM + m; re at [e*128 + d], im at [e*128 + 64 + d]
    const int e = gh * NM + m;
    buf[e * 128 + lane]      = hr;
    buf[e * 128 + 64 + lane] = hi;
    if (lane == 0) {
        totalA[2 * e]     = cr;
        totalA[2 * e + 1] = ci;
    }
}

// ---------------- Kernel B: single-m 64-lane waves, prefix + final scan (unchanged R19) ----------------
__global__ __launch_bounds__(256) void final_kernel(
    const float* __restrict__ A_bar, const float* __restrict__ K,
    const float* __restrict__ V, const float* __restrict__ beta,
    const float* __restrict__ totalA, const float* __restrict__ buf,
    float* __restrict__ Y)
{
    __shared__ float K_l[NCH][ND];
    __shared__ float A_l[NCH][8], V_l[NCH][8];
    __shared__ float b_l[NCH];

    const int blk  = blockIdx.x;         // 0..2047
    const int gh   = blk >> 3;           // g*NH + hh
    const int mblk = blk & 7;
    const int hh   = gh & (NH - 1);
    const int g    = gh >> 3;
    const int tid  = threadIdx.x;
    const int wv   = tid >> 6;
    const int lane = tid & 63;
    const int m    = mblk * 4 + wv;

    stage_slim(A_bar, K, V, beta, g, hh, mblk, K_l, A_l, V_l, b_l);

    // ---- prefix for this m: fold s = A_gg * s + H_gg over gg < g ----
    float hr = 0.f, hi = 0.f;
    for (int gg = 0; gg < g; ++gg) {
        const int e = (gg * NH + hh) * NM + m;
        const float ar = totalA[2 * e], ai = totalA[2 * e + 1];
        const float fr = buf[e * 128 + lane];
        const float fi = buf[e * 128 + 64 + lane];
        const float n = ar * hr - ai * hi + fr;
        hi = ar * hi + ai * hr + fi;
        hr = n;
    }

    // ---- final scan with init = s_in; state IS the output ----
    const int base_l = g * NCH;
    const int c0 = 2 * wv;
#pragma unroll 4
    for (int t = 0; t < NCH; ++t) {
        const float kd = K_l[t][lane];
        const float b  = b_l[t];
        const float ar = A_l[t][c0], ai = A_l[t][c0 + 1];
        const float vr = V_l[t][c0], vi = V_l[t][c0 + 1];
        const float bk = b * kd;

        const float hkr = wave_sum_bcast(hr * kd);
        const float hki = wave_sum_bcast(hi * kd);

        const float tr = hr - bk * hkr, ti = hi - bk * hki;
        hr = ar * tr - ai * ti + bk * vr;
        hi = ar * ti + ai * tr + bk * vi;

        // Y[b,l,h,2m,d]=Re, Y[b,l,h,2m+1,d]=Im — 256 B/wave contiguous stores
        const int ybase = ((base_l + t) * NH + hh) * (2 * NM) * ND + lane;
        __builtin_nontemporal_store(hr, &Y[ybase + (2 * m) * ND]);
        __builtin_nontemporal_store(hi, &Y[ybase + (2 * m + 1) * ND]);
    }
}

extern "C" void kernel_launch(void* const* d_in, const int* in_sizes, int n_in,
                              void* d_out, int out_size, void* d_ws, size_t ws_size,
                              hipStream_t stream) {
    const float* A_bar = (const float*)d_in[0];
    const float* K     = (const float*)d_in[1];
    const float* V     = (const float*)d_in[2];
    const float* beta  = (const float*)d_in[3];
    float* Y = (float*)d_out;

    float* ws = (float*)d_ws;
    float* totalA = ws;                 // NC*NH*NM*2 = 16384 floats
    float* buf    = ws + 16384;         // finalH planar: 1,048,576 floats (4 MB)

    intra_kernel<<<(NC - 1) * NH * 8, 256, 0, stream>>>(A_bar, K, V, beta, totalA, buf);
    final_kernel<<<NC * NH * 8, 256, 0, stream>>>(A_bar, K, V, beta, totalA, buf, Y);
}

// Round 22
// 44.715 us; speedup vs baseline: 1.2085x; 1.2045x over previous
//
#include <hip/hip_runtime.h>

#define NH 8
#define ND 64
#define NM 32
#define NCH 32   // sub-chunk size
#define NC 32    // num sub-chunks

typedef float f32x4 __attribute__((ext_vector_type(4)));

// ---- 16-lane-group allreduce, pure VALU butterfly (no readlane) ----
__device__ __forceinline__ float grp16_sum(float x) {
    x += __int_as_float(__builtin_amdgcn_update_dpp(0, __float_as_int(x), 0xB1, 0xf, 0xf, false));
    x += __int_as_float(__builtin_amdgcn_update_dpp(0, __float_as_int(x), 0x4E, 0xf, 0xf, false));
    x += __int_as_float(__builtin_amdgcn_update_dpp(0, __float_as_int(x), 0x141, 0xf, 0xf, false));
    x += __int_as_float(__builtin_amdgcn_update_dpp(0, __float_as_int(x), 0x140, 0xf, 0xf, false));
    return x;
}

// ---- 64-lane reduce (DPP rows + readlane bcast) — final kernel ----
__device__ __forceinline__ float wave_sum_bcast(float x) {
    float s = x;
    s += __int_as_float(__builtin_amdgcn_update_dpp(0, __float_as_int(s), 0x111, 0xf, 0xf, false));
    s += __int_as_float(__builtin_amdgcn_update_dpp(0, __float_as_int(s), 0x112, 0xf, 0xf, false));
    s += __int_as_float(__builtin_amdgcn_update_dpp(0, __float_as_int(s), 0x114, 0xf, 0xf, false));
    s += __int_as_float(__builtin_amdgcn_update_dpp(0, __float_as_int(s), 0x118, 0xf, 0xf, false));
    s += __int_as_float(__builtin_amdgcn_update_dpp(0, __float_as_int(s), 0x142, 0xa, 0xf, false));
    s += __int_as_float(__builtin_amdgcn_update_dpp(0, __float_as_int(s), 0x143, 0xc, 0xf, false));
    return __int_as_float(__builtin_amdgcn_readlane(__float_as_int(s), 63));
}

// ---------------- Kernel A: intra scan, 16-lane groups, DUAL-CHUNK ILP ----------------
// 256 blocks x 256 threads. Block = (q, hh, mhalf): chunks 2q & 2q+1, m-rows
// [16*mhalf, 16*mhalf+16). Each wave: 4 rows x 2 independent chunk-chains.
__global__ __launch_bounds__(256) void intra_kernel(
    const float* __restrict__ A_bar, const float* __restrict__ K,
    const float* __restrict__ V, const float* __restrict__ beta,
    float* __restrict__ totalA, float* __restrict__ buf)
{
    __shared__ float K_l[2][NCH][ND];           // 16 KB
    __shared__ float A_l[2][NCH][32], V_l[2][NCH][32];  // 8 KB each
    __shared__ float b_l[2][NCH];

    const int blk   = blockIdx.x;               // 0..255
    const int mhalf = blk & 1;
    const int hh    = (blk >> 1) & 7;
    const int q     = blk >> 4;                 // 0..15
    const int tid   = threadIdx.x;

    {   // stage K (full rows) for both chunks: 1024 float4s, 4/thread
#pragma unroll
        for (int i = 0; i < 4; ++i) {
            const int flat = tid + 256 * i;
            const int c = flat >> 9, rem = flat & 511;
            const int t = rem >> 4, f4 = (rem & 15) * 4;
            const int row = (((2 * q + c) * NCH + t) * NH + hh) * 64;
            *(float4*)&K_l[c][t][f4] = *(const float4*)(K + row + f4);
        }
        // stage A/V sliced to this block's 16 m-rows (32 cols): 512 float4s, 2/thread each
#pragma unroll
        for (int i = 0; i < 2; ++i) {
            const int flat = tid + 256 * i;
            const int c = flat >> 8, rem = flat & 255;
            const int t = rem >> 3, f4 = (rem & 7) * 4;
            const int row = (((2 * q + c) * NCH + t) * NH + hh) * 64 + 32 * mhalf;
            *(float4*)&A_l[c][t][f4] = *(const float4*)(A_bar + row + f4);
            *(float4*)&V_l[c][t][f4] = *(const float4*)(V + row + f4);
        }
        if (tid < 2 * NCH) {
            const int c = tid >> 5, t = tid & 31;
            b_l[c][t] = beta[((2 * q + c) * NCH + t) * NH + hh];
        }
        __syncthreads();
    }

    const int lane = tid & 63;
    const int r = lane >> 4, j = lane & 15;
    const int mloc = (tid >> 6) * 4 + r;        // 0..15 within the half
    const int m    = 16 * mhalf + mloc;         // global m

    // chunk-0 state
    float ar0_ = 0.f, ar1_ = 0.f, ar2_ = 0.f, ar3_ = 0.f;
    float ai0_ = 0.f, ai1_ = 0.f, ai2_ = 0.f, ai3_ = 0.f;
    float cAr = 1.f, cAi = 0.f;
    // chunk-1 state
    float br0_ = 0.f, br1_ = 0.f, br2_ = 0.f, br3_ = 0.f;
    float bi0_ = 0.f, bi1_ = 0.f, bi2_ = 0.f, bi3_ = 0.f;
    float cBr = 1.f, cBi = 0.f;

#pragma unroll 4
    for (int t = 0; t < NCH; ++t) {
        // ---- chunk 0 operands ----
        const float4 kA = *(const float4*)(&K_l[0][t][4 * j]);
        const float2 aA = *(const float2*)(&A_l[0][t][2 * mloc]);
        const float2 vA = *(const float2*)(&V_l[0][t][2 * mloc]);
        const float  bA = b_l[0][t];
        // ---- chunk 1 operands ----
        const float4 kB = *(const float4*)(&K_l[1][t][4 * j]);
        const float2 aB = *(const float2*)(&A_l[1][t][2 * mloc]);
        const float2 vB = *(const float2*)(&V_l[1][t][2 * mloc]);
        const float  bB = b_l[1][t];

        // two independent dot+reduce chains
        float srA = (ar0_ * kA.x + ar1_ * kA.y) + (ar2_ * kA.z + ar3_ * kA.w);
        float siA = (ai0_ * kA.x + ai1_ * kA.y) + (ai2_ * kA.z + ai3_ * kA.w);
        float srB = (br0_ * kB.x + br1_ * kB.y) + (br2_ * kB.z + br3_ * kB.w);
        float siB = (bi0_ * kB.x + bi1_ * kB.y) + (bi2_ * kB.z + bi3_ * kB.w);
        srA = grp16_sum(srA);  siA = grp16_sum(siA);
        srB = grp16_sum(srB);  siB = grp16_sum(siB);

        float tr, ti, bk;
        // chunk 0 update
        bk = bA * kA.x; tr = ar0_ - bk * srA; ti = ai0_ - bk * siA;
        ar0_ = aA.x * tr - aA.y * ti + bk * vA.x;  ai0_ = aA.x * ti + aA.y * tr + bk * vA.y;
        bk = bA * kA.y; tr = ar1_ - bk * srA; ti = ai1_ - bk * siA;
        ar1_ = aA.x * tr - aA.y * ti + bk * vA.x;  ai1_ = aA.x * ti + aA.y * tr + bk * vA.y;
        bk = bA * kA.z; tr = ar2_ - bk * srA; ti = ai2_ - bk * siA;
        ar2_ = aA.x * tr - aA.y * ti + bk * vA.x;  ai2_ = aA.x * ti + aA.y * tr + bk * vA.y;
        bk = bA * kA.w; tr = ar3_ - bk * srA; ti = ai3_ - bk * siA;
        ar3_ = aA.x * tr - aA.y * ti + bk * vA.x;  ai3_ = aA.x * ti + aA.y * tr + bk * vA.y;
        // chunk 1 update
        bk = bB * kB.x; tr = br0_ - bk * srB; ti = bi0_ - bk * siB;
        br0_ = aB.x * tr - aB.y * ti + bk * vB.x;  bi0_ = aB.x * ti + aB.y * tr + bk * vB.y;
        bk = bB * kB.y; tr = br1_ - bk * srB; ti = bi1_ - bk * siB;
        br1_ = aB.x * tr - aB.y * ti + bk * vB.x;  bi1_ = aB.x * ti + aB.y * tr + bk * vB.y;
        bk = bB * kB.z; tr = br2_ - bk * srB; ti = bi2_ - bk * siB;
        br2_ = aB.x * tr - aB.y * ti + bk * vB.x;  bi2_ = aB.x * ti + aB.y * tr + bk * vB.y;
        bk = bB * kB.w; tr = br3_ - bk * srB; ti = bi3_ - bk * siB;
        br3_ = aB.x * tr - aB.y * ti + bk * vB.x;  bi3_ = aB.x * ti + aB.y * tr + bk * vB.y;

        float n;
        n = cAr * aA.x - cAi * aA.y; cAi = cAr * aA.y + cAi * aA.x; cAr = n;
        n = cBr * aB.x - cBi * aB.y; cBi = cBr * aB.y + cBi * aB.x; cBr = n;
    }

    // write summaries (planar buf: entry stride 128 floats)
    const int e0 = ((2 * q) * NH + hh) * NM + m;
    const int e1 = ((2 * q + 1) * NH + hh) * NM + m;
    *(float4*)&buf[e0 * 128 + 4 * j]      = make_float4(ar0_, ar1_, ar2_, ar3_);
    *(float4*)&buf[e0 * 128 + 64 + 4 * j] = make_float4(ai0_, ai1_, ai2_, ai3_);
    *(float4*)&buf[e1 * 128 + 4 * j]      = make_float4(br0_, br1_, br2_, br3_);
    *(float4*)&buf[e1 * 128 + 64 + 4 * j] = make_float4(bi0_, bi1_, bi2_, bi3_);
    if (j == 0) {
        totalA[2 * e0] = cAr;  totalA[2 * e0 + 1] = cAi;
        totalA[2 * e1] = cBr;  totalA[2 * e1 + 1] = cBi;
    }
}

// ---------------- Kernel B: single-m 64-lane waves, prefix + final scan (R19, unchanged) ----------------
__global__ __launch_bounds__(256) void final_kernel(
    const float* __restrict__ A_bar, const float* __restrict__ K,
    const float* __restrict__ V, const float* __restrict__ beta,
    const float* __restrict__ totalA, const float* __restrict__ buf,
    float* __restrict__ Y)
{
    __shared__ float K_l[NCH][ND];
    __shared__ float A_l[NCH][8], V_l[NCH][8];
    __shared__ float b_l[NCH];

    const int blk  = blockIdx.x;         // 0..2047
    const int gh   = blk >> 3;           // g*NH + hh
    const int mblk = blk & 7;
    const int hh   = gh & (NH - 1);
    const int g    = gh >> 3;
    const int tid  = threadIdx.x;
    const int wv   = tid >> 6;
    const int lane = tid & 63;
    const int m    = mblk * 4 + wv;

    {   // stage: K full; A/V slice cols [8*mblk, 8*mblk+8); beta
        const int f = tid * 8;
        const int t = f >> 6, off = f & 63;
        const int row = ((g * NCH + t) * NH + hh) * 64 + off;
        *(float4*)&K_l[t][off]     = *(const float4*)(K + row);
        *(float4*)&K_l[t][off + 4] = *(const float4*)(K + row + 4);
        const int t2 = tid >> 3, c = tid & 7;
        const int row2 = ((g * NCH + t2) * NH + hh) * 64 + 8 * mblk + c;
        A_l[t2][c] = A_bar[row2];
        V_l[t2][c] = V[row2];
        if (tid < NCH) b_l[tid] = beta[(g * NCH + tid) * NH + hh];
        __syncthreads();
    }

    // prefix for this m: fold s = A_gg * s + H_gg over gg < g
    float hr = 0.f, hi = 0.f;
    for (int gg = 0; gg < g; ++gg) {
        const int e = (gg * NH + hh) * NM + m;
        const float ar = totalA[2 * e], ai = totalA[2 * e + 1];
        const float fr = buf[e * 128 + lane];
        const float fi = buf[e * 128 + 64 + lane];
        const float n = ar * hr - ai * hi + fr;
        hi = ar * hi + ai * hr + fi;
        hr = n;
    }

    // final scan with init = s_in; state IS the output
    const int base_l = g * NCH;
    const int c0 = 2 * wv;
#pragma unroll 4
    for (int t = 0; t < NCH; ++t) {
        const float kd = K_l[t][lane];
        const float b  = b_l[t];
        const float ar = A_l[t][c0], ai = A_l[t][c0 + 1];
        const float vr = V_l[t][c0], vi = V_l[t][c0 + 1];
        const float bk = b * kd;

        const float hkr = wave_sum_bcast(hr * kd);
        const float hki = wave_sum_bcast(hi * kd);

        const float tr = hr - bk * hkr, ti = hi - bk * hki;
        hr = ar * tr - ai * ti + bk * vr;
        hi = ar * ti + ai * tr + bk * vi;

        const int ybase = ((base_l + t) * NH + hh) * (2 * NM) * ND + lane;
        __builtin_nontemporal_store(hr, &Y[ybase + (2 * m) * ND]);
        __builtin_nontemporal_store(hi, &Y[ybase + (2 * m + 1) * ND]);
    }
}

extern "C" void kernel_launch(void* const* d_in, const int* in_sizes, int n_in,
                              void* d_out, int out_size, void* d_ws, size_t ws_size,
                              hipStream_t stream) {
    const float* A_bar = (const float*)d_in[0];
    const float* K     = (const float*)d_in[1];
    const float* V     = (const float*)d_in[2];
    const float* beta  = (const float*)d_in[3];
    float* Y = (float*)d_out;

    float* ws = (float*)d_ws;
    float* totalA = ws;                 // NC*NH*NM*2 = 16384 floats
    float* buf    = ws + 16384;         // finalH planar: 1,048,576 floats (4 MB)

    intra_kernel<<<256, 256, 0, stream>>>(A_bar, K, V, beta, totalA, buf);
    final_kernel<<<NC * NH * 8, 256, 0, stream>>>(A_bar, K, V, beta, totalA, buf, Y);
}